// Round 12
// baseline (230.215 us; speedup 1.0000x reference)
//
#include <hip/hip_runtime.h>
#include <math.h>

#define BB 64
#define TT 4096
#define DD 256
#define HH 256
#define NEG_INF_F (-1e9f)
#define REP 4   // DIAGNOSTIC: x4 scores+fin bodies to surface them in rocprof

// ws layout (floats):
//   partials[2048*256] @ 0        (2 MB)
//   wkq[BB*DD]         @ 524288
//   ek[BB]             @ 540672
//   e[BB*TT]           @ 540736

// ---------------- Kernel 1: per-chunk column partial sums -------------------
// (byte-identical to proven R3/R7 version)
__global__ __launch_bounds__(256) void k_colsum(const float* __restrict__ input,
                                                float* __restrict__ partials) {
    int chunk = blockIdx.x;              // 32 chunks of 128 t each
    int b = blockIdx.y;
    int tid = threadIdx.x;
    int tsub = tid >> 6;                 // 0..3
    int d4 = tid & 63;                   // float4 index over D
    const float4* base = (const float4*)(input + ((size_t)b * TT + (size_t)chunk * 128) * DD);
    float4 acc = make_float4(0.f, 0.f, 0.f, 0.f);
#pragma unroll 8
    for (int t = tsub; t < 128; t += 4) {
        float4 v = base[(size_t)t * 64 + d4];
        acc.x += v.x; acc.y += v.y; acc.z += v.z; acc.w += v.w;
    }
    __shared__ float4 sm[256];
    sm[tid] = acc;
    __syncthreads();
    if (tid < 64) {
        float4 a0 = sm[tid], a1 = sm[tid + 64], a2 = sm[tid + 128], a3 = sm[tid + 192];
        float4 r = make_float4(a0.x + a1.x + a2.x + a3.x,
                               a0.y + a1.y + a2.y + a3.y,
                               a0.z + a1.z + a2.z + a3.z,
                               a0.w + a1.w + a2.w + a3.w);
        ((float4*)(partials + ((size_t)b * 32 + chunk) * 256))[tid] = r;
    }
}

// --- Kernel 2: reduce partials -> mean; q = mean@Wq+bq ; wkq = Wk@q ; ek ----
// (byte-identical to proven R7 version)
__global__ __launch_bounds__(256) void k_small(const float* __restrict__ partials,
                                               const float* __restrict__ Wq,
                                               const float* __restrict__ bq,
                                               const float* __restrict__ Wk,
                                               const float* __restrict__ bk,
                                               float* __restrict__ wkq,
                                               float* __restrict__ ek) {
    int b = blockIdx.x, tid = threadIdx.x;
    int wave = tid >> 6, lane = tid & 63;
    __shared__ __align__(16) float mr[DD];
    __shared__ __align__(16) float qsh[HH];
    __shared__ float red[4];
    const float* pb = partials + (size_t)b * 32 * 256;
    float s = 0.f;
#pragma unroll
    for (int c = 0; c < 32; ++c) s += pb[c * 256 + tid];   // coalesced over tid
    mr[tid] = s * (1.0f / (float)TT);
    __syncthreads();
    float acc = bq[tid];
#pragma unroll 8
    for (int d = 0; d < DD; ++d) acc += mr[d] * Wq[d * HH + tid];  // coalesced
    qsh[tid] = acc;
    float p = bk[tid] * acc;
#pragma unroll
    for (int off = 32; off > 0; off >>= 1) p += __shfl_down(p, off);
    if (lane == 0) red[wave] = p;
    __syncthreads();                      // also publishes qsh
    if (tid == 0) ek[b] = red[0] + red[1] + red[2] + red[3];
    float4 qv = ((const float4*)qsh)[lane];
    for (int i = 0; i < 64; ++i) {
        int d = wave * 64 + i;
        float4 wv = ((const float4*)(Wk + (size_t)d * HH))[lane];
        float t = wv.x * qv.x + wv.y * qv.y + wv.z * qv.z + wv.w * qv.w;
#pragma unroll
        for (int off = 32; off > 0; off >>= 1) t += __shfl_down(t, off);
        if (lane == 0) wkq[b * DD + d] = t;
    }
}

// --- Kernel 3: MASK-GATED scores, 16-lane-group dot (R11) + REP diagnostic --
__global__ __launch_bounds__(256) void k_scores(const float* __restrict__ input,
                                                const float* __restrict__ wkq,
                                                const float* __restrict__ ek,
                                                const int* __restrict__ mask,
                                                const float* __restrict__ rate,
                                                float* __restrict__ e_out) {
    int job = (int)gridDim.x - 1 - (int)blockIdx.x;   // descending addresses
    int b = job >> 4;                    // 16 blocks per b
    int t0 = (job & 15) << 8;            // 256 rows per block
    int tid = threadIdx.x;
    int wave = tid >> 6, lane = tid & 63;
    int g = lane >> 4, s = lane & 15;    // 4 groups of 16 lanes per wave

    __shared__ __align__(16) float wsh[DD];
    __shared__ float esh[256];
    __shared__ int wbase[4];
    __shared__ short actlist[256];

    int m = mask[b * TT + t0 + tid];
    bool act = (m != 0);
    unsigned long long bal = __ballot(act);
    if (lane == 0) wbase[wave] = __popcll(bal);
    wsh[tid] = wkq[b * DD + tid];
    esh[tid] = NEG_INF_F;
    __syncthreads();                     // publishes wsh, wbase, esh
    int base = 0;
#pragma unroll
    for (int w = 0; w < 4; ++w) base += (w < wave) ? wbase[w] : 0;
    int nact = wbase[0] + wbase[1] + wbase[2] + wbase[3];
    int pos = base + __popcll(bal & ((1ull << lane) - 1ull));
    if (act) actlist[pos] = (short)tid;
    const float4* wsh4 = (const float4*)wsh;
    float4 w0 = wsh4[s], w1 = wsh4[16 + s], w2 = wsh4[32 + s], w3 = wsh4[48 + s];
    float ekb = ek[b];
    __syncthreads();                     // publishes actlist

    const float4* rows = (const float4*)(input + ((size_t)b * TT + t0) * DD);
#pragma unroll 1
    for (int rep = 0; rep < REP; ++rep) {
        asm volatile("" ::: "memory");   // force re-execution each rep
        for (int i0 = wave * 8; i0 < nact; i0 += 32) {
            int ia = i0 + g, ib = i0 + 4 + g;
            bool va = (ia < nact), vb = (ib < nact);
            int ra = va ? actlist[ia] : actlist[0];
            int rb = vb ? actlist[ib] : actlist[0];
            const float4* rpa = rows + (size_t)ra * 64 + s;
            const float4* rpb = rows + (size_t)rb * 64 + s;
            float4 a0 = rpa[0], a1 = rpa[16], a2 = rpa[32], a3 = rpa[48];
            float4 b0 = rpb[0], b1 = rpb[16], b2 = rpb[32], b3 = rpb[48];
            float pa = a0.x * w0.x + a0.y * w0.y + a0.z * w0.z + a0.w * w0.w
                     + a1.x * w1.x + a1.y * w1.y + a1.z * w1.z + a1.w * w1.w
                     + a2.x * w2.x + a2.y * w2.y + a2.z * w2.z + a2.w * w2.w
                     + a3.x * w3.x + a3.y * w3.y + a3.z * w3.z + a3.w * w3.w;
            float pb = b0.x * w0.x + b0.y * w0.y + b0.z * w0.z + b0.w * w0.w
                     + b1.x * w1.x + b1.y * w1.y + b1.z * w1.z + b1.w * w1.w
                     + b2.x * w2.x + b2.y * w2.y + b2.z * w2.z + b2.w * w2.w
                     + b3.x * w3.x + b3.y * w3.y + b3.z * w3.z + b3.w * w3.w;
#pragma unroll
            for (int off = 8; off > 0; off >>= 1) {
                pa += __shfl_down(pa, off, 16);
                pb += __shfl_down(pb, off, 16);
            }
            if (s == 0) {
                if (va) {
                    float e0 = pa + ekb;
                    float sg = 1.f / (1.f + expf(e0));
                    esh[ra] = e0 - rate[t0 + ra] * log1pf(sg);
                }
                if (vb) {
                    float e1 = pb + ekb;
                    float sg = 1.f / (1.f + expf(e1));
                    esh[rb] = e1 - rate[t0 + rb] * log1pf(sg);
                }
            }
        }
    }
    __syncthreads();
    e_out[b * TT + t0 + tid] = esh[tid];   // coalesced 256-wide
}

// ---- Kernel 4: sparsemax + gather + @Wv + bv, REP'd for diagnostics --------
__global__ __launch_bounds__(1024) void k_fin(const float* __restrict__ e_in,
                                              const float* __restrict__ input,
                                              const float* __restrict__ Wv,
                                              const float* __restrict__ bv,
                                              float* __restrict__ out,
                                              float* __restrict__ a_out) {
    int b = blockIdx.x, tid = threadIdx.x;
    int wave = tid >> 6, lane = tid & 63;
    __shared__ float za[TT];
    __shared__ int s_supp[TT];
    __shared__ __align__(16) float part[16 * DD];
    __shared__ __align__(16) float s_sh[DD];
    __shared__ float redM[16];
    __shared__ float redS[2][16], redC[2][16];
    __shared__ int cnt;

    const float* er = e_in + (size_t)b * TT;
#pragma unroll 1
    for (int rep = 0; rep < REP; ++rep) {
        asm volatile("" ::: "memory");    // re-execute body each rep
        float z0 = er[tid], z1 = er[tid + 1024], z2 = er[tid + 2048], z3 = er[tid + 3072];
        float lmax = fmaxf(fmaxf(z0, z1), fmaxf(z2, z3));
#pragma unroll
        for (int off = 32; off > 0; off >>= 1) lmax = fmaxf(lmax, __shfl_xor(lmax, off));
        if (lane == 0) redM[wave] = lmax;
        if (tid == 0) cnt = 0;
        __syncthreads();
        float mx = redM[0];
#pragma unroll
        for (int i = 1; i < 16; ++i) mx = fmaxf(mx, redM[i]);
        z0 = fmaxf(z0 - mx, -1.0f); z1 = fmaxf(z1 - mx, -1.0f);
        z2 = fmaxf(z2 - mx, -1.0f); z3 = fmaxf(z3 - mx, -1.0f);
        za[tid] = z0; za[tid + 1024] = z1; za[tid + 2048] = z2; za[tid + 3072] = z3;

        float tau = -1.0f;
        int prevc = -1;
        for (int it = 0; it < 32; ++it) {
            int pb = it & 1;
            float s = 0.f, c = 0.f;
            if (z0 > tau) { s += z0; c += 1.f; }
            if (z1 > tau) { s += z1; c += 1.f; }
            if (z2 > tau) { s += z2; c += 1.f; }
            if (z3 > tau) { s += z3; c += 1.f; }
#pragma unroll
            for (int off = 32; off > 0; off >>= 1) {
                s += __shfl_xor(s, off);
                c += __shfl_xor(c, off);
            }
            if (lane == 0) { redS[pb][wave] = s; redC[pb][wave] = c; }
            __syncthreads();
            float ss = 0.f, cc = 0.f;
#pragma unroll
            for (int i = 0; i < 16; ++i) { ss += redS[pb][i]; cc += redC[pb][i]; }
            tau = (ss - 1.f) / cc;
            int ci = (int)cc;
            if (ci == prevc) break;
            prevc = ci;
        }

        float a0 = fmaxf(z0 - tau, 0.f), a1 = fmaxf(z1 - tau, 0.f);
        float a2 = fmaxf(z2 - tau, 0.f), a3 = fmaxf(z3 - tau, 0.f);
        float* ar = a_out + (size_t)b * TT;
        ar[tid] = a0; ar[tid + 1024] = a1; ar[tid + 2048] = a2; ar[tid + 3072] = a3;
        if (a0 > 0.f) s_supp[atomicAdd(&cnt, 1)] = tid;
        if (a1 > 0.f) s_supp[atomicAdd(&cnt, 1)] = tid + 1024;
        if (a2 > 0.f) s_supp[atomicAdd(&cnt, 1)] = tid + 2048;
        if (a3 > 0.f) s_supp[atomicAdd(&cnt, 1)] = tid + 3072;
        float lsum = a0 + a1 + a2 + a3;
#pragma unroll
        for (int off = 32; off > 0; off >>= 1) lsum += __shfl_xor(lsum, off);
        if (lane == 0) redM[wave] = lsum;
        __syncthreads();                  // publishes redM, s_supp, cnt
        float suma = 0.f;
#pragma unroll
        for (int i = 0; i < 16; ++i) suma += redM[i];

        float4 acc = make_float4(0.f, 0.f, 0.f, 0.f);
        int cl = cnt;
        for (int i = wave; i < cl; i += 16) {
            int t = s_supp[i];
            float av = fmaxf(za[t] - tau, 0.f);
            float4 v = ((const float4*)(input + ((size_t)b * TT + t) * DD))[lane];
            acc.x += av * v.x; acc.y += av * v.y; acc.z += av * v.z; acc.w += av * v.w;
        }
        ((float4*)part)[wave * 64 + lane] = acc;
        __syncthreads();
        if (tid < 256) {
            float s = 0.f;
#pragma unroll
            for (int w = 0; w < 16; ++w) s += part[w * 256 + tid];
            s_sh[tid] = s;
        }
        __syncthreads();
        int h = tid & 255;
        int g = tid >> 8;
        float o = 0.f;
#pragma unroll 8
        for (int d = g * 64; d < g * 64 + 64; ++d) o += s_sh[d] * Wv[(size_t)d * HH + h];
        part[g * 256 + h] = o;
        __syncthreads();
        if (tid < 256) {
            float o4 = part[tid] + part[256 + tid] + part[512 + tid] + part[768 + tid]
                     + suma * bv[tid];
            out[b * HH + tid] = o4;
        }
        __syncthreads();                  // protect part[]/cnt reuse across reps
    }
}

extern "C" void kernel_launch(void* const* d_in, const int* in_sizes, int n_in,
                              void* d_out, int out_size, void* d_ws, size_t ws_size,
                              hipStream_t stream) {
    const float* input = (const float*)d_in[0];
    const int*   mask  = (const int*)d_in[1];
    const float* Wq    = (const float*)d_in[2];
    const float* bq    = (const float*)d_in[3];
    const float* Wk    = (const float*)d_in[4];
    const float* bk    = (const float*)d_in[5];
    const float* Wv    = (const float*)d_in[6];
    const float* bv    = (const float*)d_in[7];
    const float* rate  = (const float*)d_in[8];

    float* out   = (float*)d_out;            // (B,H)
    float* a_out = out + BB * HH;            // (B,T)

    float* ws       = (float*)d_ws;
    float* partials = ws;                    // 2048*256
    float* wkq      = ws + 524288;           // BB*DD
    float* ek       = ws + 540672;           // BB
    float* e        = ws + 540736;           // BB*TT

    k_colsum<<<dim3(32, BB), 256, 0, stream>>>(input, partials);
    k_small<<<BB, 256, 0, stream>>>(partials, Wq, bq, Wk, bk, wkq, ek);
    k_scores<<<(BB * TT) / 256, 256, 0, stream>>>(input, wkq, ek, mask, rate, e);
    k_fin<<<BB, 1024, 0, stream>>>(e, input, Wv, bv, out, a_out);
}

// Round 13
// 108.033 us; speedup vs baseline: 2.1310x; 2.1310x over previous
//
#include <hip/hip_runtime.h>
#include <math.h>

#define BB 64
#define TT 4096
#define DD 256
#define HH 256
#define NEG_INF_F (-1e9f)

// ws layout (floats):
//   partials[2048*256] @ 0        (2 MB)
//   e[BB*TT]           @ 524288

// ---------------- Kernel 1: per-chunk column partial sums -------------------
// (byte-identical to proven R3/R7 version)
__global__ __launch_bounds__(256) void k_colsum(const float* __restrict__ input,
                                                float* __restrict__ partials) {
    int chunk = blockIdx.x;              // 32 chunks of 128 t each
    int b = blockIdx.y;
    int tid = threadIdx.x;
    int tsub = tid >> 6;                 // 0..3
    int d4 = tid & 63;                   // float4 index over D
    const float4* base = (const float4*)(input + ((size_t)b * TT + (size_t)chunk * 128) * DD);
    float4 acc = make_float4(0.f, 0.f, 0.f, 0.f);
#pragma unroll 8
    for (int t = tsub; t < 128; t += 4) {
        float4 v = base[(size_t)t * 64 + d4];
        acc.x += v.x; acc.y += v.y; acc.z += v.z; acc.w += v.w;
    }
    __shared__ float4 sm[256];
    sm[tid] = acc;
    __syncthreads();
    if (tid < 64) {
        float4 a0 = sm[tid], a1 = sm[tid + 64], a2 = sm[tid + 128], a3 = sm[tid + 192];
        float4 r = make_float4(a0.x + a1.x + a2.x + a3.x,
                               a0.y + a1.y + a2.y + a3.y,
                               a0.z + a1.z + a2.z + a3.z,
                               a0.w + a1.w + a2.w + a3.w);
        ((float4*)(partials + ((size_t)b * 32 + chunk) * 256))[tid] = r;
    }
}

// --- Kernel 2: FAST fused prefix (mean->q->wkq,ek) + mask-gated scores ------
// Prefix rebuilt on 16-lane groups (R12 showed the R8 prefix's 64-iter shfl
// matvec was ~10us critical path; this one is ~3-4us). Body: 4 independent
// dot chains per group for MLP. 1024 blocks, descending, 256 rows each.
__global__ __launch_bounds__(256) void k_scores(const float* __restrict__ input,
                                                const float* __restrict__ partials,
                                                const float* __restrict__ Wq,
                                                const float* __restrict__ bq,
                                                const float* __restrict__ Wk,
                                                const float* __restrict__ bk,
                                                const int* __restrict__ mask,
                                                const float* __restrict__ rate,
                                                float* __restrict__ e_out) {
    int job = (int)gridDim.x - 1 - (int)blockIdx.x;   // descending addresses
    int b = job >> 4;                    // 16 blocks per b
    int t0 = (job & 15) << 8;            // 256 rows per block
    int tid = threadIdx.x;
    int wave = tid >> 6, lane = tid & 63;
    int g = lane >> 4, s = lane & 15;    // 4 groups of 16 lanes per wave

    __shared__ __align__(16) float mr[DD];
    __shared__ __align__(16) float qsh[HH];
    __shared__ __align__(16) float wsh[DD];
    __shared__ float esh[256];
    __shared__ float red[4];
    __shared__ int wbase[4];
    __shared__ short actlist[256];

    // ---- mask compaction start + partials reduce ----
    int m = mask[b * TT + t0 + tid];
    bool act = (m != 0);
    unsigned long long bal = __ballot(act);
    if (lane == 0) wbase[wave] = __popcll(bal);
    const float* pbp = partials + (size_t)b * 32 * 256;
    float ssum = 0.f;
#pragma unroll
    for (int c = 0; c < 32; ++c) ssum += pbp[c * 256 + tid];   // coalesced, L2-hot
    mr[tid] = ssum * (1.0f / (float)TT);
    esh[tid] = NEG_INF_F;
    __syncthreads();                     // publishes mr, wbase, esh
    int base = 0;
#pragma unroll
    for (int w = 0; w < 4; ++w) base += (w < wave) ? wbase[w] : 0;
    int nact = wbase[0] + wbase[1] + wbase[2] + wbase[3];
    int pos = base + __popcll(bal & ((1ull << lane) - 1ull));
    if (act) actlist[pos] = (short)tid;

    // ---- q = mean@Wq + bq (coalesced Wq reads, L2-broadcast-hot) ----
    float q = bq[tid];
#pragma unroll 8
    for (int d = 0; d < DD; ++d) q += mr[d] * Wq[d * HH + tid];
    qsh[tid] = q;
    float p = bk[tid] * q;
#pragma unroll
    for (int off = 32; off > 0; off >>= 1) p += __shfl_down(p, off);
    if (lane == 0) red[wave] = p;
    __syncthreads();                     // publishes qsh, red, actlist
    float ekb = red[0] + red[1] + red[2] + red[3];   // uniform

    // ---- wkq = Wk@q via 16-lane groups: 16 groups x 16 rows, 4-shfl reduce --
    const float4* q4 = (const float4*)qsh;
    float4 q0 = q4[s], q1 = q4[16 + s], q2 = q4[32 + s], q3 = q4[48 + s];
    int grp = wave * 4 + g;              // 0..15
#pragma unroll 4
    for (int j = 0; j < 16; ++j) {
        int d = grp * 16 + j;
        const float4* wk4 = (const float4*)(Wk + (size_t)d * HH);
        float4 r0 = wk4[s], r1 = wk4[16 + s], r2 = wk4[32 + s], r3 = wk4[48 + s];
        float t = r0.x * q0.x + r0.y * q0.y + r0.z * q0.z + r0.w * q0.w
                + r1.x * q1.x + r1.y * q1.y + r1.z * q1.z + r1.w * q1.w
                + r2.x * q2.x + r2.y * q2.y + r2.z * q2.z + r2.w * q2.w
                + r3.x * q3.x + r3.y * q3.y + r3.z * q3.z + r3.w * q3.w;
#pragma unroll
        for (int off = 8; off > 0; off >>= 1) t += __shfl_down(t, off, 16);
        if (s == 0) wsh[d] = t;
    }
    __syncthreads();                     // publishes wsh

    // ---- streaming body: 16 active rows per wave-iter (4 per group, MLP) ---
    const float4* wsh4 = (const float4*)wsh;
    float4 w0 = wsh4[s], w1 = wsh4[16 + s], w2 = wsh4[32 + s], w3 = wsh4[48 + s];
    const float4* rows = (const float4*)(input + ((size_t)b * TT + t0) * DD);
    for (int i0 = wave * 16; i0 < nact; i0 += 64) {
        int ia = i0 + g, ib = i0 + 4 + g, ic = i0 + 8 + g, id_ = i0 + 12 + g;
        bool va = (ia < nact), vb = (ib < nact), vc = (ic < nact), vd = (id_ < nact);
        int ra = va ? actlist[ia] : actlist[0];
        int rb = vb ? actlist[ib] : actlist[0];
        int rc = vc ? actlist[ic] : actlist[0];
        int rd = vd ? actlist[id_] : actlist[0];
        const float4* rpa = rows + (size_t)ra * 64 + s;
        const float4* rpb = rows + (size_t)rb * 64 + s;
        const float4* rpc = rows + (size_t)rc * 64 + s;
        const float4* rpd = rows + (size_t)rd * 64 + s;
        float4 a0 = rpa[0], a1 = rpa[16], a2 = rpa[32], a3 = rpa[48];
        float4 b0 = rpb[0], b1 = rpb[16], b2 = rpb[32], b3 = rpb[48];
        float4 c0 = rpc[0], c1 = rpc[16], c2 = rpc[32], c3 = rpc[48];
        float4 d0 = rpd[0], d1 = rpd[16], d2 = rpd[32], d3 = rpd[48];
        float pa = a0.x * w0.x + a0.y * w0.y + a0.z * w0.z + a0.w * w0.w
                 + a1.x * w1.x + a1.y * w1.y + a1.z * w1.z + a1.w * w1.w
                 + a2.x * w2.x + a2.y * w2.y + a2.z * w2.z + a2.w * w2.w
                 + a3.x * w3.x + a3.y * w3.y + a3.z * w3.z + a3.w * w3.w;
        float pb = b0.x * w0.x + b0.y * w0.y + b0.z * w0.z + b0.w * w0.w
                 + b1.x * w1.x + b1.y * w1.y + b1.z * w1.z + b1.w * w1.w
                 + b2.x * w2.x + b2.y * w2.y + b2.z * w2.z + b2.w * w2.w
                 + b3.x * w3.x + b3.y * w3.y + b3.z * w3.z + b3.w * w3.w;
        float pc = c0.x * w0.x + c0.y * w0.y + c0.z * w0.z + c0.w * w0.w
                 + c1.x * w1.x + c1.y * w1.y + c1.z * w1.z + c1.w * w1.w
                 + c2.x * w2.x + c2.y * w2.y + c2.z * w2.z + c2.w * w2.w
                 + c3.x * w3.x + c3.y * w3.y + c3.z * w3.z + c3.w * w3.w;
        float pd = d0.x * w0.x + d0.y * w0.y + d0.z * w0.z + d0.w * w0.w
                 + d1.x * w1.x + d1.y * w1.y + d1.z * w1.z + d1.w * w1.w
                 + d2.x * w2.x + d2.y * w2.y + d2.z * w2.z + d2.w * w2.w
                 + d3.x * w3.x + d3.y * w3.y + d3.z * w3.z + d3.w * w3.w;
#pragma unroll
        for (int off = 8; off > 0; off >>= 1) {    // 4 independent chains
            pa += __shfl_down(pa, off, 16);
            pb += __shfl_down(pb, off, 16);
            pc += __shfl_down(pc, off, 16);
            pd += __shfl_down(pd, off, 16);
        }
        if (s == 0) {
            if (va) { float e0 = pa + ekb; float sg = 1.f / (1.f + expf(e0));
                      esh[ra] = e0 - rate[t0 + ra] * log1pf(sg); }
            if (vb) { float e1 = pb + ekb; float sg = 1.f / (1.f + expf(e1));
                      esh[rb] = e1 - rate[t0 + rb] * log1pf(sg); }
            if (vc) { float e2 = pc + ekb; float sg = 1.f / (1.f + expf(e2));
                      esh[rc] = e2 - rate[t0 + rc] * log1pf(sg); }
            if (vd) { float e3 = pd + ekb; float sg = 1.f / (1.f + expf(e3));
                      esh[rd] = e3 - rate[t0 + rd] * log1pf(sg); }
        }
    }
    __syncthreads();
    e_out[b * TT + t0 + tid] = esh[tid];   // coalesced 256-wide
}

// ---- Kernel 3: sparsemax (seeded Michelot) + gather + @Wv + bv -------------
// (byte-identical to proven version)
__global__ __launch_bounds__(1024) void k_fin(const float* __restrict__ e_in,
                                              const float* __restrict__ input,
                                              const float* __restrict__ Wv,
                                              const float* __restrict__ bv,
                                              float* __restrict__ out,
                                              float* __restrict__ a_out) {
    int b = blockIdx.x, tid = threadIdx.x;
    int wave = tid >> 6, lane = tid & 63;
    __shared__ float za[TT];                       // 16 KB
    __shared__ int s_supp[TT];                     // 16 KB (worst case all-active)
    __shared__ __align__(16) float part[16 * DD];  // 16 KB
    __shared__ __align__(16) float s_sh[DD];
    __shared__ float redM[16];
    __shared__ float redS[2][16], redC[2][16];
    __shared__ int cnt;

    const float* er = e_in + (size_t)b * TT;
    float z0 = er[tid], z1 = er[tid + 1024], z2 = er[tid + 2048], z3 = er[tid + 3072];
    float lmax = fmaxf(fmaxf(z0, z1), fmaxf(z2, z3));
#pragma unroll
    for (int off = 32; off > 0; off >>= 1) lmax = fmaxf(lmax, __shfl_xor(lmax, off));
    if (lane == 0) redM[wave] = lmax;
    if (tid == 0) cnt = 0;
    __syncthreads();
    float mx = redM[0];
#pragma unroll
    for (int i = 1; i < 16; ++i) mx = fmaxf(mx, redM[i]);  // uniform LDS broadcast
    // clamp to -1: lossless (support always has z-zmax > -1), kills NEG_INF rows
    z0 = fmaxf(z0 - mx, -1.0f); z1 = fmaxf(z1 - mx, -1.0f);
    z2 = fmaxf(z2 - mx, -1.0f); z3 = fmaxf(z3 - mx, -1.0f);
    za[tid] = z0; za[tid + 1024] = z1; za[tid + 2048] = z2; za[tid + 3072] = z3;

    // Michelot fixed point seeded at tau=-1 (support subset of {z > zmax-1}):
    // ~2-4 iterations; one barrier/iter via double-buffered reductions.
    float tau = -1.0f;
    int prevc = -1;
    for (int it = 0; it < 32; ++it) {
        int pb = it & 1;
        float s = 0.f, c = 0.f;
        if (z0 > tau) { s += z0; c += 1.f; }
        if (z1 > tau) { s += z1; c += 1.f; }
        if (z2 > tau) { s += z2; c += 1.f; }
        if (z3 > tau) { s += z3; c += 1.f; }
#pragma unroll
        for (int off = 32; off > 0; off >>= 1) {
            s += __shfl_xor(s, off);
            c += __shfl_xor(c, off);
        }
        if (lane == 0) { redS[pb][wave] = s; redC[pb][wave] = c; }
        __syncthreads();
        float ss = 0.f, cc = 0.f;
#pragma unroll
        for (int i = 0; i < 16; ++i) { ss += redS[pb][i]; cc += redC[pb][i]; }
        tau = (ss - 1.f) / cc;            // identical across all threads
        int ci = (int)cc;
        if (ci == prevc) break;           // set stable => fixed point
        prevc = ci;
    }

    // a, a_out, support list, suma
    float a0 = fmaxf(z0 - tau, 0.f), a1 = fmaxf(z1 - tau, 0.f);
    float a2 = fmaxf(z2 - tau, 0.f), a3 = fmaxf(z3 - tau, 0.f);
    float* ar = a_out + (size_t)b * TT;
    ar[tid] = a0; ar[tid + 1024] = a1; ar[tid + 2048] = a2; ar[tid + 3072] = a3;
    if (a0 > 0.f) s_supp[atomicAdd(&cnt, 1)] = tid;
    if (a1 > 0.f) s_supp[atomicAdd(&cnt, 1)] = tid + 1024;
    if (a2 > 0.f) s_supp[atomicAdd(&cnt, 1)] = tid + 2048;
    if (a3 > 0.f) s_supp[atomicAdd(&cnt, 1)] = tid + 3072;
    float lsum = a0 + a1 + a2 + a3;
#pragma unroll
    for (int off = 32; off > 0; off >>= 1) lsum += __shfl_xor(lsum, off);
    if (lane == 0) redM[wave] = lsum;
    __syncthreads();                      // publishes redM, s_supp, cnt
    float suma = 0.f;
#pragma unroll
    for (int i = 0; i < 16; ++i) suma += redM[i];  // uniform

    // gather: s[d] = sum_{t in supp} a_t * input[b,t,d], waves split supp
    float4 acc = make_float4(0.f, 0.f, 0.f, 0.f);
    int cl = cnt;
    for (int i = wave; i < cl; i += 16) {
        int t = s_supp[i];
        float av = fmaxf(za[t] - tau, 0.f);
        float4 v = ((const float4*)(input + ((size_t)b * TT + t) * DD))[lane];
        acc.x += av * v.x; acc.y += av * v.y; acc.z += av * v.z; acc.w += av * v.w;
    }
    ((float4*)part)[wave * 64 + lane] = acc;
    __syncthreads();
    if (tid < 256) {
        float s = 0.f;
#pragma unroll
        for (int w = 0; w < 16; ++w) s += part[w * 256 + tid];
        s_sh[tid] = s;
    }
    __syncthreads();
    // out[h] = sum_d s[d]*Wv[d][h] + suma*bv[h]; 4 groups of 256 threads split d
    int h = tid & 255;
    int g = tid >> 8;                  // 0..3
    float o = 0.f;
#pragma unroll 8
    for (int d = g * 64; d < g * 64 + 64; ++d) o += s_sh[d] * Wv[(size_t)d * HH + h];
    part[g * 256 + h] = o;
    __syncthreads();
    if (tid < 256) {
        float o4 = part[tid] + part[256 + tid] + part[512 + tid] + part[768 + tid]
                 + suma * bv[tid];
        out[b * HH + tid] = o4;
    }
}

extern "C" void kernel_launch(void* const* d_in, const int* in_sizes, int n_in,
                              void* d_out, int out_size, void* d_ws, size_t ws_size,
                              hipStream_t stream) {
    const float* input = (const float*)d_in[0];
    const int*   mask  = (const int*)d_in[1];
    const float* Wq    = (const float*)d_in[2];
    const float* bq    = (const float*)d_in[3];
    const float* Wk    = (const float*)d_in[4];
    const float* bk    = (const float*)d_in[5];
    const float* Wv    = (const float*)d_in[6];
    const float* bv    = (const float*)d_in[7];
    const float* rate  = (const float*)d_in[8];

    float* out   = (float*)d_out;            // (B,H)
    float* a_out = out + BB * HH;            // (B,T)

    float* ws       = (float*)d_ws;
    float* partials = ws;                    // 2048*256
    float* e        = ws + 524288;           // BB*TT

    k_colsum<<<dim3(32, BB), 256, 0, stream>>>(input, partials);
    k_scores<<<(BB * TT) / 256, 256, 0, stream>>>(input, partials, Wq, bq, Wk, bk,
                                                  mask, rate, e);
    k_fin<<<BB, 1024, 0, stream>>>(e, input, Wv, bv, out, a_out);
}